// Round 9
// baseline (66.634 us; speedup 1.0000x reference)
//
#include <hip/hip_runtime.h>

#define B_ 32
#define T_ 4096
#define D_ 256
#define A_ 128

typedef __attribute__((ext_vector_type(8))) short bf16x8;
typedef __attribute__((ext_vector_type(4))) float f32x4;
typedef __attribute__((address_space(3))) void lds_void_t;
typedef const __attribute__((address_space(1))) void gbl_void_t;

__device__ __forceinline__ ushort f32_to_bf16_rne(float x) {
    uint u = __float_as_uint(x);
    u = (u + 0x7FFFu + ((u >> 16) & 1u)) >> 16;
    return (ushort)u;
}
__device__ __forceinline__ float bf16_bits_to_f32(ushort b) {
    return __uint_as_float(((uint)b) << 16);
}

// fast tanh: 1 - 2/(e^{2x}+1); exp overflow -> +-1 naturally.
__device__ __forceinline__ float fast_tanh(float x) {
    float t = __expf(2.0f * x);
    float r = __builtin_amdgcn_rcpf(t + 1.0f);
    return fmaf(-2.0f, r, 1.0f);
}

// split 8 f32 -> hi bf16x8 (round-half-up) + lo bf16x8 (exact residual)
__device__ __forceinline__ void split8(float4 a, float4 b, bf16x8& hi8, bf16x8& lo8) {
    float xs[8] = {a.x, a.y, a.z, a.w, b.x, b.y, b.z, b.w};
    union { uint w[4]; bf16x8 v; } H, L;
#pragma unroll
    for (int p = 0; p < 4; ++p) {
        float x0 = xs[2 * p], x1 = xs[2 * p + 1];
        uint r0 = __float_as_uint(x0) + 0x8000u;
        uint r1 = __float_as_uint(x1) + 0x8000u;
        H.w[p] = __builtin_amdgcn_perm(r1, r0, 0x07060302u);
        float rem0 = x0 - __uint_as_float(r0 & 0xFFFF0000u);
        float rem1 = x1 - __uint_as_float(r1 & 0xFFFF0000u);
        L.w[p] = __builtin_amdgcn_perm(__float_as_uint(rem1), __float_as_uint(rem0), 0x07060302u);
    }
    hi8 = H.v;
    lo8 = L.v;
}

// -----------------------------------------------------------------------------
// Kernel 0: build the pre-swizzled W LDS image (128 KB).
// Image byte addr = ph*32768 + p*16384 + r*128 + s'*16, holding bf16 plane p
// (0=hi,1=lo) of W[r][ph*64 + (s'^(r&7))*8 .. +8]. A straight 32KB memcpy of
// chunk ph into LDS then yields the swizzled layout the MFMA loop reads.
// -----------------------------------------------------------------------------
__global__ __launch_bounds__(256) void convert_W_kernel(
    const float* __restrict__ W, ushort* __restrict__ Wimg)
{
    const int c   = blockIdx.x * 256 + threadIdx.x;   // 16B chunk id, 0..8191
    const int ph  = c >> 11;
    const int p   = (c >> 10) & 1;
    const int r   = (c >> 3) & 127;
    const int sp  = c & 7;
    const int s   = sp ^ (r & 7);
    const float* src = W + (size_t)r * D_ + ph * 64 + s * 8;

    union { ushort us[8]; float4 v; } out;
#pragma unroll
    for (int i = 0; i < 8; ++i) {
        float x = src[i];
        ushort hb = f32_to_bf16_rne(x);
        out.us[i] = p ? f32_to_bf16_rne(x - bf16_bits_to_f32(hb)) : hb;
    }
    *reinterpret_cast<float4*>(Wimg + (size_t)c * 8) = out.v;
}

// -----------------------------------------------------------------------------
// Kernel 1 (fused): score (split-bf16 MFMA) + flash-local pool.
// - W staged via global_load_lds from the pre-swizzled image, double-buffered
//   (2 x 32KB), one raw s_barrier per phase with COUNTED vmcnt (8/8/4) so the
//   rolling h prefetch stream survives every barrier.
// - Block = 4 waves x 32 rows (rt=2) = 128 rows = one flash chunk; grid 1024.
// - Pool re-reads the block's own 128 rows (L2/L3-hot) - no register retention.
// -----------------------------------------------------------------------------
__global__ __launch_bounds__(256, 2) void score_pool_kernel(
    const float* __restrict__ h, const ushort* __restrict__ Wimg,
    const float* __restrict__ bw, const float* __restrict__ uw,
    float* __restrict__ part, float2* __restrict__ stats)
{
    __shared__ char wlds[65536];        // 2 bufs x [plane][row][swz slot]
    __shared__ float sc[128];
    __shared__ float elds[128];
    __shared__ float ssum[2];
    __shared__ float4 redp[4][64];

    const int tid  = threadIdx.x;
    const int w    = tid >> 6;
    const int lane = tid & 63;
    const int l15  = lane & 15;
    const int l4   = lane >> 4;
    const int rowbase = blockIdx.x * 128 + w * 32;

    const char* gWb = (const char*)Wimg + w * 1024 + lane * 16;

#define WSTAGE(buf, ph)                                                        \
    {                                                                          \
        _Pragma("unroll")                                                      \
        for (int i = 0; i < 8; ++i)                                            \
            __builtin_amdgcn_global_load_lds(                                  \
                (gbl_void_t*)(gWb + (ph) * 32768 + i * 4096),                  \
                (lds_void_t*)(wlds + (buf) * 32768 + w * 1024 + i * 4096),     \
                16, 0, 0);                                                     \
    }

    const float* hrow0 = h + (size_t)(rowbase + l15) * D_ + l4 * 8;
    const float* hrow1 = hrow0 + 16 * D_;

    float4 hbuf[8][2][2];
#define PREF(s)                                                                \
    {                                                                          \
        hbuf[s][0][0] = *reinterpret_cast<const float4*>(hrow0 + (s) * 32);    \
        hbuf[s][0][1] = *reinterpret_cast<const float4*>(hrow0 + (s) * 32 + 4);\
        hbuf[s][1][0] = *reinterpret_cast<const float4*>(hrow1 + (s) * 32);    \
        hbuf[s][1][1] = *reinterpret_cast<const float4*>(hrow1 + (s) * 32 + 4);\
    }

    f32x4 acc[2][8];
#pragma unroll
    for (int rt = 0; rt < 2; ++rt)
#pragma unroll
        for (int j = 0; j < 8; ++j)
#pragma unroll
            for (int r = 0; r < 4; ++r) acc[rt][j][r] = 0.f;

    // ---- prologue: stage buf0, start h stream, counted wait ----
    WSTAGE(0, 0);
    __builtin_amdgcn_sched_barrier(0);
    PREF(0); PREF(1); PREF(2);
    asm volatile("s_waitcnt vmcnt(12)" ::: "memory");   // buf0 landed, 12 h in flight
    __builtin_amdgcn_sched_barrier(0);
    __builtin_amdgcn_s_barrier();
    __builtin_amdgcn_sched_barrier(0);

#pragma unroll
    for (int ph = 0; ph < 4; ++ph) {
        const int cur = ph & 1;
        if (ph < 3) WSTAGE(cur ^ 1, ph + 1);
        __builtin_amdgcn_sched_barrier(0);   // pin: stage ops precede phase loads

#pragma unroll
        for (int st = 0; st < 2; ++st) {
            const int stg = ph * 2 + st;
            if (stg + 3 < 8) PREF(stg + 3);

            bf16x8 ahi[2], alo[2];
            split8(hbuf[stg][0][0], hbuf[stg][0][1], ahi[0], alo[0]);
            split8(hbuf[stg][1][0], hbuf[stg][1][1], ahi[1], alo[1]);

            const int slotbase = st * 4 + l4;
#pragma unroll
            for (int j = 0; j < 8; ++j) {
                const int r   = j * 16 + l15;
                const int off = cur * 32768 + r * 128 + ((slotbase ^ (r & 7)) << 4);
                bf16x8 wh = *reinterpret_cast<const bf16x8*>(wlds + off);
                bf16x8 wl = *reinterpret_cast<const bf16x8*>(wlds + 16384 + off);
                acc[0][j] = __builtin_amdgcn_mfma_f32_16x16x32_bf16(ahi[0], wh, acc[0][j], 0, 0, 0);
                acc[0][j] = __builtin_amdgcn_mfma_f32_16x16x32_bf16(alo[0], wh, acc[0][j], 0, 0, 0);
                acc[0][j] = __builtin_amdgcn_mfma_f32_16x16x32_bf16(ahi[0], wl, acc[0][j], 0, 0, 0);
                acc[1][j] = __builtin_amdgcn_mfma_f32_16x16x32_bf16(ahi[1], wh, acc[1][j], 0, 0, 0);
                acc[1][j] = __builtin_amdgcn_mfma_f32_16x16x32_bf16(alo[1], wh, acc[1][j], 0, 0, 0);
                acc[1][j] = __builtin_amdgcn_mfma_f32_16x16x32_bf16(ahi[1], wl, acc[1][j], 0, 0, 0);
            }
        }

        if (ph < 3) {
            // counted wait: next buf landed, newest h prefetches stay in flight
            if (ph == 2) { asm volatile("s_waitcnt vmcnt(4)" ::: "memory"); }
            else         { asm volatile("s_waitcnt vmcnt(8)" ::: "memory"); }
            __builtin_amdgcn_sched_barrier(0);
            __builtin_amdgcn_s_barrier();
            __builtin_amdgcn_sched_barrier(0);
        }
    }
#undef WSTAGE
#undef PREF

    // ---- scores for the wave's 32 rows ----
    float rsum[2][4];
#pragma unroll
    for (int rt = 0; rt < 2; ++rt)
#pragma unroll
        for (int r = 0; r < 4; ++r) rsum[rt][r] = 0.f;

#pragma unroll
    for (int j = 0; j < 8; ++j) {
        const float bwv = bw[j * 16 + l15];
        const float uwv = uw[j * 16 + l15];
#pragma unroll
        for (int rt = 0; rt < 2; ++rt)
#pragma unroll
            for (int r = 0; r < 4; ++r)
                rsum[rt][r] = fmaf(fast_tanh(acc[rt][j][r] + bwv), uwv, rsum[rt][r]);
    }
#pragma unroll
    for (int rt = 0; rt < 2; ++rt)
#pragma unroll
        for (int r = 0; r < 4; ++r) {
#pragma unroll
            for (int m = 1; m < 16; m <<= 1)
                rsum[rt][r] += __shfl_xor(rsum[rt][r], m, 64);
        }
    if (l15 == 0) {
#pragma unroll
        for (int rt = 0; rt < 2; ++rt)
#pragma unroll
            for (int r = 0; r < 4; ++r)
                sc[w * 32 + rt * 16 + l4 * 4 + r] = rsum[rt][r];
    }
    __syncthreads();

    // ---- flash-local softmax over the block's 128 rows ----
    float m_c = -3.0e38f;
#pragma unroll 16
    for (int t = 0; t < 128; ++t) m_c = fmaxf(m_c, sc[t]);   // LDS broadcast

    if (tid < 128) {
        float e = __expf(sc[tid] - m_c);
        elds[tid] = e;
        float s = e;
#pragma unroll
        for (int msk = 1; msk < 64; msk <<= 1) s += __shfl_xor(s, msk, 64);
        if ((tid & 63) == 0) ssum[tid >> 6] = s;
    }
    __syncthreads();
    if (tid == 0) stats[blockIdx.x] = make_float2(m_c, ssum[0] + ssum[1]);

    // ---- pool: P_c[d] = sum_t e_t * h[t][d]  (L2/L3-hot re-read) ----
    const int d4 = tid & 63;
    const int tr = tid >> 6;
    const float* hp = h + (size_t)blockIdx.x * 128 * D_;
    float4 pacc = {0.f, 0.f, 0.f, 0.f};
#pragma unroll
    for (int i = 0; i < 32; ++i) {
        const int r = i * 4 + tr;
        float4 v = *reinterpret_cast<const float4*>(hp + (size_t)r * D_ + d4 * 4);
        const float e = elds[r];
        pacc.x = fmaf(e, v.x, pacc.x);
        pacc.y = fmaf(e, v.y, pacc.y);
        pacc.z = fmaf(e, v.z, pacc.z);
        pacc.w = fmaf(e, v.w, pacc.w);
    }
    redp[tr][d4] = pacc;
    __syncthreads();
    if (tr == 0) {
        float4 s0 = redp[0][d4], s1 = redp[1][d4], s2 = redp[2][d4], s3 = redp[3][d4];
        float4 o = {s0.x + s1.x + s2.x + s3.x, s0.y + s1.y + s2.y + s3.y,
                    s0.z + s1.z + s2.z + s3.z, s0.w + s1.w + s2.w + s3.w};
        *reinterpret_cast<float4*>(part + (size_t)blockIdx.x * D_ + d4 * 4) = o;
    }
}

// -----------------------------------------------------------------------------
// Kernel 2: exact flash combine per batch over its 32 chunk-partials.
// out[b][d] = sum_c exp(m_c-M)*P_c[d] / sum_c exp(m_c-M)*s_c,  M = max_c m_c.
// -----------------------------------------------------------------------------
__global__ __launch_bounds__(256) void combine_kernel(
    const float* __restrict__ part, const float2* __restrict__ stats,
    float* __restrict__ out)
{
    const int b = blockIdx.x;
    const int t = threadIdx.x;

    __shared__ float cw[32];

    if (t < 32) {
        const float2 st = stats[b * 32 + t];
        float M = st.x;
#pragma unroll
        for (int msk = 1; msk < 32; msk <<= 1) M = fmaxf(M, __shfl_xor(M, msk, 64));
        const float em = __expf(st.x - M);
        float S = em * st.y;
#pragma unroll
        for (int msk = 1; msk < 32; msk <<= 1) S += __shfl_xor(S, msk, 64);
        cw[t] = em / S;
    }
    __syncthreads();

    float acc = 0.f;
    const float* pb = part + (size_t)b * 32 * D_ + t;
#pragma unroll 8
    for (int c = 0; c < 32; ++c)
        acc = fmaf(cw[c], pb[(size_t)c * D_], acc);
    out[b * D_ + t] = acc;
}

extern "C" void kernel_launch(void* const* d_in, const int* in_sizes, int n_in,
                              void* d_out, int out_size, void* d_ws, size_t ws_size,
                              hipStream_t stream) {
    const float* h  = (const float*)d_in[0];
    const float* W  = (const float*)d_in[1];
    const float* bw = (const float*)d_in[2];
    const float* uw = (const float*)d_in[3];
    float* out = (float*)d_out;

    ushort* Wimg  = (ushort*)d_ws;                          // 128 KB
    float*  part  = (float*)(Wimg + (size_t)65536);         // 1024*256*4 = 1 MB
    float2* stats = (float2*)(part + (size_t)1024 * D_);    // 8 KB

    convert_W_kernel<<<dim3(32), 256, 0, stream>>>(W, Wimg);
    score_pool_kernel<<<dim3((B_ * T_) / 128), 256, 0, stream>>>(h, Wimg, bw, uw, part, stats);
    combine_kernel<<<dim3(B_), 256, 0, stream>>>(part, stats, out);
}